// Round 1
// baseline (771.989 us; speedup 1.0000x reference)
//
#include <hip/hip_runtime.h>

typedef unsigned short u16;
typedef __attribute__((ext_vector_type(8))) short bf16x8;   // 8 bf16 in 4 VGPRs
typedef __attribute__((ext_vector_type(4))) float f32x4;

__device__ __forceinline__ u16 f2bf(float f) {
    unsigned u = __float_as_uint(f);
    u += 0x7fffu + ((u >> 16) & 1u);   // round-to-nearest-even
    return (u16)(u >> 16);
}

__device__ __forceinline__ void g2l16(const void* g, void* l) {
    __builtin_amdgcn_global_load_lds((const __attribute__((address_space(1))) void*)g,
                                     (__attribute__((address_space(3))) void*)l, 16, 0, 0);
}

// ---------------------------------------------------------------------------
// GEMM: C[M,N] = alpha * A[M,K] @ B^T  where B is stored [N,K] row-major.
// bf16 inputs, fp32 accumulate. 128x128 tile, BK=64, 4 waves of 4x4 16x16x32.
// XOR-swizzled LDS chunk layout (swizzle applied on the global source side so
// global_load_lds's forced base+lane*16 LDS addressing still works).
// causal_skip: skip blocks with bx>by (upper triangle, never read).
// causal_kcap: K capped at (by+1)*128 (A columns beyond are zero).
// ---------------------------------------------------------------------------
#define BM 128
#define BN 128
#define BK 64

template <bool OUT_BF16>
__global__ __launch_bounds__(256, 2) void gemm_bt(
    const u16* __restrict__ A, const u16* __restrict__ B, void* __restrict__ Cout,
    int M, int N, int K, int lda, int ldb, int ldc,
    long long sA, long long sB, long long sC,
    float alpha, int causal_skip, int causal_kcap)
{
    const int bx = blockIdx.x, by = blockIdx.y, bz = blockIdx.z;
    if (causal_skip && bx > by) return;
    int Keff = K;
    if (causal_kcap) { int cap = (by + 1) * BM; if (cap < Keff) Keff = cap; }

    __shared__ alignas(16) u16 As[BM * BK];
    __shared__ alignas(16) u16 Bs[BN * BK];

    const int tid  = threadIdx.x;
    const int wave = tid >> 6, lane = tid & 63;
    const int wm = wave >> 1, wn = wave & 1;
    const int q = lane >> 4, r = lane & 15;

    const u16* Ab = A + sA * bz + (size_t)(by * BM) * lda;
    const u16* Bb = B + sB * bz + (size_t)(bx * BN) * ldb;

    f32x4 acc[4][4] = {};

    const int kiters = Keff / BK;
    for (int kt = 0; kt < kiters; ++kt) {
        const int k0 = kt * BK;
#pragma unroll
        for (int j = 0; j < 4; ++j) {         // A tile: 128 rows x 8 chunks(16B)
            int sb  = (wave * 4 + j) * 64;
            int s   = sb + lane;
            int row = s >> 3;
            int cc  = (s & 7) ^ (row & 7);    // slot s holds global chunk cc of row
            g2l16(Ab + (size_t)row * lda + (k0 + cc * 8), As + (size_t)sb * 8);
        }
#pragma unroll
        for (int j = 0; j < 4; ++j) {         // B tile
            int sb  = (wave * 4 + j) * 64;
            int s   = sb + lane;
            int row = s >> 3;
            int cc  = (s & 7) ^ (row & 7);
            g2l16(Bb + (size_t)row * ldb + (k0 + cc * 8), Bs + (size_t)sb * 8);
        }
        __syncthreads();
#pragma unroll
        for (int ks = 0; ks < 2; ++ks) {      // two 32-wide k-steps per tile
            bf16x8 af[4], bfv[4];
#pragma unroll
            for (int i = 0; i < 4; ++i) {
                int mr = wm * 64 + i * 16 + r;
                int cc = (ks * 4 + q) ^ (mr & 7);
                af[i] = *(const bf16x8*)(As + mr * BK + cc * 8);
            }
#pragma unroll
            for (int i = 0; i < 4; ++i) {
                int nr = wn * 64 + i * 16 + r;
                int cc = (ks * 4 + q) ^ (nr & 7);
                bfv[i] = *(const bf16x8*)(Bs + nr * BK + cc * 8);
            }
#pragma unroll
            for (int i = 0; i < 4; ++i)
#pragma unroll
                for (int jn = 0; jn < 4; ++jn)
                    acc[i][jn] = __builtin_amdgcn_mfma_f32_16x16x32_bf16(
                        af[i], bfv[jn], acc[i][jn], 0, 0, 0);
        }
        __syncthreads();
    }

    // epilogue: C/D layout col=lane&15, row=(lane>>4)*4+reg
    if constexpr (OUT_BF16) {
        u16* Cp = (u16*)Cout + sC * bz;
#pragma unroll
        for (int i = 0; i < 4; ++i) {
            int rowb = by * BM + wm * 64 + i * 16 + q * 4;
#pragma unroll
            for (int jn = 0; jn < 4; ++jn) {
                int col = bx * BN + wn * 64 + jn * 16 + r;
#pragma unroll
                for (int rr = 0; rr < 4; ++rr)
                    Cp[(size_t)(rowb + rr) * ldc + col] = f2bf(acc[i][jn][rr] * alpha);
            }
        }
    } else {
        float* Cp = (float*)Cout + sC * bz;
#pragma unroll
        for (int i = 0; i < 4; ++i) {
            int rowb = by * BM + wm * 64 + i * 16 + q * 4;
#pragma unroll
            for (int jn = 0; jn < 4; ++jn) {
                int col = bx * BN + wn * 64 + jn * 16 + r;
#pragma unroll
                for (int rr = 0; rr < 4; ++rr)
                    Cp[(size_t)(rowb + rr) * ldc + col] = acc[i][jn][rr] * alpha;
            }
        }
    }
}

// fp32 -> bf16 elementwise cast (x). Exact grid: n/1024 blocks.
__global__ void cast_f32_bf16(const float4* __restrict__ in, ushort4* __restrict__ out) {
    int i = blockIdx.x * 256 + threadIdx.x;
    float4 f = in[i];
    ushort4 o;
    o.x = f2bf(f.x); o.y = f2bf(f.y); o.z = f2bf(f.z); o.w = f2bf(f.w);
    out[i] = o;
}

// transpose + cast: in fp32 [R][Cc] -> out bf16 [Cc][R]
__global__ void transpose_cast_f32(const float* __restrict__ in, u16* __restrict__ out,
                                   int R, int Cc) {
    __shared__ u16 tile[32][33];
    int tx = threadIdx.x, ty = threadIdx.y;
    int c0 = blockIdx.x * 32, r0 = blockIdx.y * 32;
#pragma unroll
    for (int k = 0; k < 4; ++k)
        tile[ty + k * 8][tx] = f2bf(in[(size_t)(r0 + ty + k * 8) * Cc + c0 + tx]);
    __syncthreads();
#pragma unroll
    for (int k = 0; k < 4; ++k)
        out[(size_t)(c0 + ty + k * 8) * R + r0 + tx] = tile[tx][ty + k * 8];
}

// transpose bf16 with strides + batch: in [R][Cc] (rowstride ldin) -> out [Cc][R]
__global__ void transpose_bf16(const u16* __restrict__ in, u16* __restrict__ out,
                               int R, int Cc, int ldin, int ldout,
                               long long sIn, long long sOut) {
    __shared__ u16 tile[32][33];
    in  += (long long)blockIdx.z * sIn;
    out += (long long)blockIdx.z * sOut;
    int tx = threadIdx.x, ty = threadIdx.y;
    int c0 = blockIdx.x * 32, r0 = blockIdx.y * 32;
#pragma unroll
    for (int k = 0; k < 4; ++k)
        tile[ty + k * 8][tx] = in[(size_t)(r0 + ty + k * 8) * ldin + c0 + tx];
    __syncthreads();
#pragma unroll
    for (int k = 0; k < 4; ++k)
        out[(size_t)(c0 + ty + k * 8) * ldout + r0 + tx] = tile[tx][ty + k * 8];
}

// causal softmax over one row of S (fp32, already scaled), writes bf16 A.
// Row t: valid s in [0, t]; zero-fills s > t (needed for the a@v K-cap).
__global__ __launch_bounds__(256) void softmax_causal(
    const float* __restrict__ S, u16* __restrict__ A, int T, long long sS)
{
    const int t = blockIdx.x;
    const float* row = S + (long long)blockIdx.y * sS + (size_t)t * T;
    u16* orow = A + (long long)blockIdx.y * sS + (size_t)t * T;
    const int n = t + 1;
    const int tid = threadIdx.x;

    float v[8];
    float m = -1e30f;
#pragma unroll
    for (int k = 0; k < 2; ++k) {
        float4 f = ((const float4*)row)[k * 256 + tid];
        int e = (k * 256 + tid) * 4;
        v[k * 4 + 0] = (e + 0 < n) ? f.x : -1e30f;
        v[k * 4 + 1] = (e + 1 < n) ? f.y : -1e30f;
        v[k * 4 + 2] = (e + 2 < n) ? f.z : -1e30f;
        v[k * 4 + 3] = (e + 3 < n) ? f.w : -1e30f;
    }
#pragma unroll
    for (int j = 0; j < 8; ++j) m = fmaxf(m, v[j]);

    __shared__ float red[4];
    for (int off = 32; off > 0; off >>= 1) m = fmaxf(m, __shfl_xor(m, off));
    int wave = tid >> 6, lane = tid & 63;
    if (lane == 0) red[wave] = m;
    __syncthreads();
    m = fmaxf(fmaxf(red[0], red[1]), fmaxf(red[2], red[3]));

    float s = 0.f;
#pragma unroll
    for (int j = 0; j < 8; ++j) { v[j] = __expf(v[j] - m); s += v[j]; }
    for (int off = 32; off > 0; off >>= 1) s += __shfl_xor(s, off);
    __syncthreads();
    if (lane == 0) red[wave] = s;
    __syncthreads();
    s = red[0] + red[1] + red[2] + red[3];
    float inv = 1.f / s;

#pragma unroll
    for (int k = 0; k < 2; ++k) {
        ushort4 o;
        o.x = f2bf(v[k * 4 + 0] * inv);
        o.y = f2bf(v[k * 4 + 1] * inv);
        o.z = f2bf(v[k * 4 + 2] * inv);
        o.w = f2bf(v[k * 4 + 3] * inv);
        ((ushort4*)orow)[k * 256 + tid] = o;
    }
}

extern "C" void kernel_launch(void* const* d_in, const int* in_sizes, int n_in,
                              void* d_out, int out_size, void* d_ws, size_t ws_size,
                              hipStream_t stream)
{
    const float* x     = (const float*)d_in[0];
    const float* Wqkv  = (const float*)d_in[1];
    const float* Wproj = (const float*)d_in[2];
    float* out = (float*)d_out;

    const int Bb = 8, T = 2048, C1 = 1024, C3 = 3072;

    // workspace layout (bytes)
    char* ws = (char*)d_ws;
    u16*  xb     = (u16*)(ws);                       //  32 MB  x as bf16 [B*T, C]
    u16*  WqkvT  = (u16*)(ws +  33554432ULL);        //   6 MB  [3C, C]
    u16*  WprojT = (u16*)(ws +  39845888ULL);        //   2 MB  [C, C]
    u16*  qkvb   = (u16*)(ws +  41943040ULL);        //  96 MB  [B*T, 3C]
    u16*  vT     = (u16*)(ws + 142606336ULL);        //  32 MB  [B][C, T]
    u16*  attnb  = (u16*)(ws + 176160768ULL);        //  32 MB  [B*T, C]
    float* Sbuf  = (float*)(ws + 209715200ULL);      // 128 MB full / 16 MB per-batch
    const bool full = ws_size >= 411041792ULL;
    u16*  Asm_   = (u16*)(ws + (full ? 343932928ULL : 226492416ULL));

    // 1. cast x -> bf16   (16.7M elems, exact grid)
    cast_f32_bf16<<<16384, 256, 0, stream>>>((const float4*)x, (ushort4*)xb);

    // 2. transpose+cast weights
    transpose_cast_f32<<<dim3(96, 32), dim3(32, 8), 0, stream>>>(Wqkv,  WqkvT,  C1, C3);
    transpose_cast_f32<<<dim3(32, 32), dim3(32, 8), 0, stream>>>(Wproj, WprojT, C1, C1);

    // 3. qkv = x @ Wqkv   [16384,1024]x[1024,3072] -> bf16 [16384,3072]
    gemm_bt<true><<<dim3(24, 128, 1), 256, 0, stream>>>(
        xb, WqkvT, qkvb, Bb * T, C3, C1, C1, C1, C3, 0, 0, 0, 1.0f, 0, 0);

    // 4. vT[b][c][s] = v[b][s][c]   (v = qkv cols [2C,3C))
    transpose_bf16<<<dim3(32, 64, 8), dim3(32, 8), 0, stream>>>(
        qkvb + 2 * C1, vT, T, C1, C3, T, (long long)T * C3, (long long)C1 * T);

    // 5. attention per batch (z=8 batched if workspace allows, else loop)
    const int iters = full ? 1 : Bb;
    const int zdim  = full ? Bb : 1;
    for (int i = 0; i < iters; ++i) {
        const u16* qb  = qkvb + (long long)i * T * C3;
        const u16* kb  = qb + C1;
        const u16* vtb = vT + (long long)i * C1 * T;
        u16* ab = attnb + (long long)i * T * C1;

        // S = (q @ k^T) * C^-0.5, fp32, causal block-skip
        gemm_bt<false><<<dim3(16, 16, zdim), 256, 0, stream>>>(
            qb, kb, Sbuf, T, T, C1, C3, C3, T,
            full ? (long long)T * C3 : 0, full ? (long long)T * C3 : 0,
            full ? (long long)T * T : 0, 0.03125f, 1, 0);

        // A = causal softmax(S), bf16, zero-filled above diagonal
        softmax_causal<<<dim3(T, zdim), 256, 0, stream>>>(
            Sbuf, Asm_, T, (long long)T * T);

        // attn = A @ v  (B^T = vT [C,T]), K capped causally
        gemm_bt<true><<<dim3(8, 16, zdim), 256, 0, stream>>>(
            Asm_, vtb, ab, T, C1, T, T, T, C1,
            full ? (long long)T * T : 0, full ? (long long)C1 * T : 0,
            full ? (long long)T * C1 : 0, 1.0f, 0, 1);
    }

    // 6. out = attn @ Wproj  -> fp32 d_out
    gemm_bt<false><<<dim3(8, 128, 1), 256, 0, stream>>>(
        attnb, WprojT, out, Bb * T, C1, C1, C1, C1, C1, 0, 0, 0, 1.0f, 0, 0);

    (void)in_sizes; (void)n_in; (void)out_size;
}

// Round 2
// 471.676 us; speedup vs baseline: 1.6367x; 1.6367x over previous
//
#include <hip/hip_runtime.h>

typedef unsigned short u16;
typedef __attribute__((ext_vector_type(8))) short bf16x8;   // 8 bf16 in 4 VGPRs
typedef __attribute__((ext_vector_type(4))) float f32x4;

__device__ __forceinline__ u16 f2bf(float f) {
    unsigned u = __float_as_uint(f);
    u += 0x7fffu + ((u >> 16) & 1u);   // round-to-nearest-even
    return (u16)(u >> 16);
}

__device__ __forceinline__ void g2l16(const void* g, void* l) {
    __builtin_amdgcn_global_load_lds((const __attribute__((address_space(1))) void*)g,
                                     (__attribute__((address_space(3))) void*)l, 16, 0, 0);
}

// ---------------------------------------------------------------------------
// GEMM: C[M,N] = alpha * A[M,K] @ B^T  where B is stored [N,K] row-major.
// bf16 in, fp32 accum. 128x128 tile, BK=64, 4 waves x (4x4 of 16x16x32 MFMA).
// XOR chunk swizzle applied on the GLOBAL source side so global_load_lds's
// forced base+lane*16 LDS addressing yields a conflict-free LDS layout
// (verified: SQ_LDS_BANK_CONFLICT == 0 in round 1).
// causal_skip: skip blocks with bx>by (upper triangle, never read).
// causal_kcap: K capped at (by+1)*128 (A cols beyond are zero from softmax).
// ---------------------------------------------------------------------------
#define BM 128
#define BN 128
#define BK 64

template <bool OUT_BF16>
__global__ __launch_bounds__(256, 4) void gemm_bt(
    const u16* __restrict__ A, const u16* __restrict__ B, void* __restrict__ Cout,
    int M, int N, int K, int lda, int ldb, int ldc,
    long long sA, long long sB, long long sC,
    float alpha, int causal_skip, int causal_kcap)
{
    const int bx = blockIdx.x, by = blockIdx.y, bz = blockIdx.z;
    if (causal_skip && bx > by) return;
    int Keff = K;
    if (causal_kcap) { int cap = (by + 1) * BM; if (cap < Keff) Keff = cap; }

    __shared__ alignas(16) u16 As[BM * BK];
    __shared__ alignas(16) u16 Bs[BN * BK];

    const int tid  = threadIdx.x;
    const int wave = tid >> 6, lane = tid & 63;
    const int wm = wave >> 1, wn = wave & 1;
    const int q = lane >> 4, r = lane & 15;

    const u16* Ab = A + sA * bz + (size_t)(by * BM) * lda;
    const u16* Bb = B + sB * bz + (size_t)(bx * BN) * ldb;

    f32x4 acc[4][4] = {};

    const int kiters = Keff / BK;
    for (int kt = 0; kt < kiters; ++kt) {
        const int k0 = kt * BK;
#pragma unroll
        for (int j = 0; j < 4; ++j) {         // A tile: 128 rows x 8 chunks(16B)
            int sb  = (wave * 4 + j) * 64;
            int s   = sb + lane;
            int row = s >> 3;
            int cc  = (s & 7) ^ (row & 7);    // slot s holds global chunk cc of row
            g2l16(Ab + (size_t)row * lda + (k0 + cc * 8), As + (size_t)sb * 8);
        }
#pragma unroll
        for (int j = 0; j < 4; ++j) {         // B tile
            int sb  = (wave * 4 + j) * 64;
            int s   = sb + lane;
            int row = s >> 3;
            int cc  = (s & 7) ^ (row & 7);
            g2l16(Bb + (size_t)row * ldb + (k0 + cc * 8), Bs + (size_t)sb * 8);
        }
        __syncthreads();
#pragma unroll
        for (int ks = 0; ks < 2; ++ks) {      // two 32-wide k-steps per tile
            bf16x8 af[4], bfv[4];
#pragma unroll
            for (int i = 0; i < 4; ++i) {
                int mr = wm * 64 + i * 16 + r;
                int cc = (ks * 4 + q) ^ (mr & 7);
                af[i] = *(const bf16x8*)(As + mr * BK + cc * 8);
            }
#pragma unroll
            for (int i = 0; i < 4; ++i) {
                int nr = wn * 64 + i * 16 + r;
                int cc = (ks * 4 + q) ^ (nr & 7);
                bfv[i] = *(const bf16x8*)(Bs + nr * BK + cc * 8);
            }
#pragma unroll
            for (int i = 0; i < 4; ++i)
#pragma unroll
                for (int jn = 0; jn < 4; ++jn)
                    acc[i][jn] = __builtin_amdgcn_mfma_f32_16x16x32_bf16(
                        af[i], bfv[jn], acc[i][jn], 0, 0, 0);
        }
        __syncthreads();
    }

    // epilogue: C/D layout col=lane&15, row=(lane>>4)*4+reg
    if constexpr (OUT_BF16) {
        u16* Cp = (u16*)Cout + sC * bz;
#pragma unroll
        for (int i = 0; i < 4; ++i) {
            int rowb = by * BM + wm * 64 + i * 16 + q * 4;
#pragma unroll
            for (int jn = 0; jn < 4; ++jn) {
                int col = bx * BN + wn * 64 + jn * 16 + r;
#pragma unroll
                for (int rr = 0; rr < 4; ++rr)
                    Cp[(size_t)(rowb + rr) * ldc + col] = f2bf(acc[i][jn][rr] * alpha);
            }
        }
    } else {
        float* Cp = (float*)Cout + sC * bz;
#pragma unroll
        for (int i = 0; i < 4; ++i) {
            int rowb = by * BM + wm * 64 + i * 16 + q * 4;
#pragma unroll
            for (int jn = 0; jn < 4; ++jn) {
                int col = bx * BN + wn * 64 + jn * 16 + r;
#pragma unroll
                for (int rr = 0; rr < 4; ++rr)
                    Cp[(size_t)(rowb + rr) * ldc + col] = acc[i][jn][rr] * alpha;
            }
        }
    }
}

// fp32 -> bf16 elementwise cast (x). Exact grid: n/1024 blocks.
__global__ void cast_f32_bf16(const float4* __restrict__ in, ushort4* __restrict__ out) {
    int i = blockIdx.x * 256 + threadIdx.x;
    float4 f = in[i];
    ushort4 o;
    o.x = f2bf(f.x); o.y = f2bf(f.y); o.z = f2bf(f.z); o.w = f2bf(f.w);
    out[i] = o;
}

// transpose + cast: in fp32 [R][Cc] -> out bf16 [Cc][R]
__global__ void transpose_cast_f32(const float* __restrict__ in, u16* __restrict__ out,
                                   int R, int Cc) {
    __shared__ u16 tile[32][33];
    int tx = threadIdx.x, ty = threadIdx.y;
    int c0 = blockIdx.x * 32, r0 = blockIdx.y * 32;
#pragma unroll
    for (int k = 0; k < 4; ++k)
        tile[ty + k * 8][tx] = f2bf(in[(size_t)(r0 + ty + k * 8) * Cc + c0 + tx]);
    __syncthreads();
#pragma unroll
    for (int k = 0; k < 4; ++k)
        out[(size_t)(c0 + ty + k * 8) * R + r0 + tx] = tile[tx][ty + k * 8];
}

// transpose bf16 with strides + batch: in [R][Cc] (rowstride ldin) -> out [Cc][R]
__global__ void transpose_bf16(const u16* __restrict__ in, u16* __restrict__ out,
                               int R, int Cc, int ldin, int ldout,
                               long long sIn, long long sOut) {
    __shared__ u16 tile[32][33];
    in  += (long long)blockIdx.z * sIn;
    out += (long long)blockIdx.z * sOut;
    int tx = threadIdx.x, ty = threadIdx.y;
    int c0 = blockIdx.x * 32, r0 = blockIdx.y * 32;
#pragma unroll
    for (int k = 0; k < 4; ++k)
        tile[ty + k * 8][tx] = in[(size_t)(r0 + ty + k * 8) * ldin + c0 + tx];
    __syncthreads();
#pragma unroll
    for (int k = 0; k < 4; ++k)
        out[(size_t)(c0 + ty + k * 8) * ldout + r0 + tx] = tile[tx][ty + k * 8];
}

// In-place causal softmax, one WAVE per row. Reads the fp32 score row S[t][:],
// writes bf16 probabilities over the same bytes (row stride stays T fp32 =
// 2T bf16). Only reads cols [0, t]; writes/zero-fills [0, roundup128(t+1))
// which is exactly what the kcap'd a@v GEMM consumes.
__global__ __launch_bounds__(256) void softmax_causal_ip(
    float* __restrict__ S, int T, long long sS)
{
    const int wave = threadIdx.x >> 6, lane = threadIdx.x & 63;
    const int t = blockIdx.x * 4 + wave;
    float* row = S + (long long)blockIdx.y * sS + (size_t)t * T;
    const int n = t + 1;
    const int L = (n + 127) & ~127;        // kcap'd row length (multiple of 128)
    const int nit = (L + 255) >> 8;        // chunks of 64 lanes x 4 floats, <=8

    float v[32];
    float m = -1e30f;
    for (int it = 0; it < nit; ++it) {
        int c = it * 64 + lane;
        int e = c * 4;
        float4 f = make_float4(-1e30f, -1e30f, -1e30f, -1e30f);
        if (e < n) f = ((const float4*)row)[c];
        v[it * 4 + 0] = (e + 0 < n) ? f.x : -1e30f;
        v[it * 4 + 1] = (e + 1 < n) ? f.y : -1e30f;
        v[it * 4 + 2] = (e + 2 < n) ? f.z : -1e30f;
        v[it * 4 + 3] = (e + 3 < n) ? f.w : -1e30f;
        m = fmaxf(m, fmaxf(fmaxf(v[it * 4 + 0], v[it * 4 + 1]),
                           fmaxf(v[it * 4 + 2], v[it * 4 + 3])));
    }
    for (int off = 32; off > 0; off >>= 1) m = fmaxf(m, __shfl_xor(m, off));

    float s = 0.f;
    for (int it = 0; it < nit; ++it) {
#pragma unroll
        for (int j = 0; j < 4; ++j) {
            v[it * 4 + j] = __expf(v[it * 4 + j] - m);
            s += v[it * 4 + j];
        }
    }
    for (int off = 32; off > 0; off >>= 1) s += __shfl_xor(s, off);
    float inv = 1.f / s;

    u16* orow = (u16*)row;
    for (int it = 0; it < nit; ++it) {
        int c = it * 64 + lane;
        if (c * 4 < L) {
            ushort4 o;
            o.x = f2bf(v[it * 4 + 0] * inv);
            o.y = f2bf(v[it * 4 + 1] * inv);
            o.z = f2bf(v[it * 4 + 2] * inv);
            o.w = f2bf(v[it * 4 + 3] * inv);
            ((ushort4*)orow)[c] = o;
        }
    }
}

extern "C" void kernel_launch(void* const* d_in, const int* in_sizes, int n_in,
                              void* d_out, int out_size, void* d_ws, size_t ws_size,
                              hipStream_t stream)
{
    const float* x     = (const float*)d_in[0];
    const float* Wqkv  = (const float*)d_in[1];
    const float* Wproj = (const float*)d_in[2];
    float* out = (float*)d_out;

    const int Bb = 8, T = 2048, C1 = 1024, C3 = 3072;

    // workspace layout (bytes) — attnb overlays xb (dead after qkv GEMM);
    // bf16 A overlays fp32 S in place (row stride T fp32 = 2T bf16).
    char* ws = (char*)d_ws;
    u16*  xb     = (u16*)(ws);                       //  32 MB  x bf16 [B*T, C]
    u16*  attnb  = (u16*)(ws);                       //  32 MB  overlay (post-qkv)
    u16*  WqkvT  = (u16*)(ws +  33554432ULL);        //   6 MB  [3C, C]
    u16*  WprojT = (u16*)(ws +  39845888ULL);        //   2 MB  [C, C]
    u16*  qkvb   = (u16*)(ws +  41943040ULL);        //  96 MB  [B*T, 3C]
    u16*  vT     = (u16*)(ws + 142606336ULL);        //  32 MB  [B][C, T]
    float* Sbuf  = (float*)(ws + 176160768ULL);      //  z*16 MB scores / probs

    // largest batch-chunk whose score buffer fits the workspace
    int zc = 1;
    if      (ws_size >= 176160768ULL + 8ULL * 16777216ULL) zc = 8;
    else if (ws_size >= 176160768ULL + 4ULL * 16777216ULL) zc = 4;
    else if (ws_size >= 176160768ULL + 2ULL * 16777216ULL) zc = 2;

    // 1. cast x -> bf16   (16.7M elems, exact grid)
    cast_f32_bf16<<<16384, 256, 0, stream>>>((const float4*)x, (ushort4*)xb);

    // 2. transpose+cast weights
    transpose_cast_f32<<<dim3(96, 32), dim3(32, 8), 0, stream>>>(Wqkv,  WqkvT,  C1, C3);
    transpose_cast_f32<<<dim3(32, 32), dim3(32, 8), 0, stream>>>(Wproj, WprojT, C1, C1);

    // 3. qkv = x @ Wqkv   [16384,1024]x[1024,3072] -> bf16 [16384,3072]
    gemm_bt<true><<<dim3(24, 128, 1), 256, 0, stream>>>(
        xb, WqkvT, qkvb, Bb * T, C3, C1, C1, C1, C3, 0, 0, 0, 1.0f, 0, 0);

    // 4. vT[b][c][s] = v[b][s][c]   (v = qkv cols [2C,3C))
    transpose_bf16<<<dim3(32, 64, 8), dim3(32, 8), 0, stream>>>(
        qkvb + 2 * C1, vT, T, C1, C3, T, (long long)T * C3, (long long)C1 * T);

    // 5. attention, zc batches at a time
    for (int i = 0; i < Bb; i += zc) {
        const u16* qb  = qkvb + (long long)i * T * C3;
        const u16* kb  = qb + C1;
        const u16* vtb = vT + (long long)i * C1 * T;
        u16* ab = attnb + (long long)i * T * C1;

        // S = (q @ k^T) * C^-0.5, fp32, causal block-skip
        gemm_bt<false><<<dim3(16, 16, zc), 256, 0, stream>>>(
            qb, kb, Sbuf, T, T, C1, C3, C3, T,
            (long long)T * C3, (long long)T * C3, (long long)T * T,
            0.03125f, 1, 0);

        // A = causal softmax(S), bf16 in place, zero-filled to roundup128(t+1)
        softmax_causal_ip<<<dim3(T / 4, zc), 256, 0, stream>>>(
            Sbuf, T, (long long)T * T);

        // attn = A @ v  (A bf16 rows at stride 2T; B^T = vT [C,T]), K kcap'd
        gemm_bt<true><<<dim3(8, 16, zc), 256, 0, stream>>>(
            (const u16*)Sbuf, vtb, ab, T, C1, T, 2 * T, T, C1,
            2LL * T * T, (long long)C1 * T, (long long)T * C1,
            1.0f, 0, 1);
    }

    // 6. out = attn @ Wproj  -> fp32 d_out
    gemm_bt<false><<<dim3(8, 128, 1), 256, 0, stream>>>(
        attnb, WprojT, out, Bb * T, C1, C1, C1, C1, C1, 0, 0, 0, 1.0f, 0, 0);

    (void)in_sizes; (void)n_in; (void)out_size;
}